// Round 1
// baseline (62.950 us; speedup 1.0000x reference)
//
#include <hip/hip_runtime.h>

#define OUT_ROWS 100
#define OUT_COLS 7

// One thread per output element. B<=8 small loop to find the last batch n
// whose ragged window [off_n, off_n+k_n) covers row r (later batches
// overwrite earlier ones in the reference's sequential scan). Rows covered
// by no window are 0 (d_out is poisoned pre-launch, so we always write).
__global__ void rv_fixed_output_kernel(const int* __restrict__ num_dets,
                                       const float* __restrict__ boxes,
                                       const float* __restrict__ scores,
                                       const float* __restrict__ classes,
                                       float* __restrict__ out,
                                       int B, int N) {
    int idx = blockIdx.x * blockDim.x + threadIdx.x;
    if (idx >= OUT_ROWS * OUT_COLS) return;
    int r = idx / OUT_COLS;
    int c = idx - r * OUT_COLS;

    float val = 0.0f;
    // Last writer wins: iterate n ascending, keep the latest match.
    for (int n = 0; n < B; ++n) {
        int off = (n == 0) ? 0 : num_dets[n - 1];
        int k = num_dets[n];
        if (r >= off && r < off + k) {
            int s = r - off;  // 0 <= s < k <= 11 < N, matches clipped gather
            long base = (long)n * N + s;
            float v;
            if (c == 0)       v = (float)n;          // vd column: batch id
            else if (c <= 4)  v = boxes[base * 4 + (c - 1)];
            else if (c == 5)  v = classes[base];
            else              v = scores[base];
            val = v;
        }
    }
    out[idx] = val;
}

extern "C" void kernel_launch(void* const* d_in, const int* in_sizes, int n_in,
                              void* d_out, int out_size, void* d_ws, size_t ws_size,
                              hipStream_t stream) {
    const int*   num_dets = (const int*)d_in[0];
    const float* boxes    = (const float*)d_in[1];
    const float* scores   = (const float*)d_in[2];
    const float* classes  = (const float*)d_in[3];
    float* out = (float*)d_out;

    int B = in_sizes[0];              // 8
    int N = in_sizes[2] / B;          // scores is [B, N] -> 8192

    // 700 output elements -> one block of 704 threads (11 waves), one dispatch.
    rv_fixed_output_kernel<<<1, 704, 0, stream>>>(num_dets, boxes, scores,
                                                  classes, out, B, N);
}